// Round 1
// baseline (144.355 us; speedup 1.0000x reference)
//
#include <hip/hip_runtime.h>
#include <math.h>

#define DD 32
#define MM 16

__device__ __forceinline__ void load8f4(const float* __restrict__ p, float* r) {
    const float4* q = (const float4*)p;
#pragma unroll
    for (int i = 0; i < 8; ++i) {
        float4 v = q[i];
        r[4*i+0] = v.x; r[4*i+1] = v.y; r[4*i+2] = v.z; r[4*i+3] = v.w;
    }
}

// Kernel 1: per-item precompute.
// tbl[i*40 + 0..31]  = t_i[d]  = sum_e W_bil[d][e] * item_e[i][e]
// tbl[i*40 + 32..39] = c_i[j]  = sum_d W1[j][64+d] * item_e[i][d]   (item-only MLP partial)
__global__ void precompute_item(const float* __restrict__ item_table,
                                const float* __restrict__ W_bil,
                                const float* __restrict__ W1,
                                float* __restrict__ tbl, int NI) {
    int i = blockIdx.x * blockDim.x + threadIdx.x;
    if (i >= NI) return;
    float it[DD];
    load8f4(item_table + (size_t)i * DD, it);
    float* o = tbl + (size_t)i * 40;
#pragma unroll 4
    for (int d = 0; d < DD; ++d) {
        float s = 0.f;
#pragma unroll
        for (int e = 0; e < DD; ++e) s = fmaf(W_bil[d * DD + e], it[e], s);
        o[d] = s;
    }
#pragma unroll
    for (int j = 0; j < 8; ++j) {
        float s = 0.f;
#pragma unroll
        for (int d = 0; d < DD; ++d) s = fmaf(W1[j * 96 + 64 + d], it[d], s);
        o[32 + j] = s;
    }
}

template <bool USE_TBL>
__global__ void bilinear_main(const int* __restrict__ item_inputs,
                              const int* __restrict__ member_ids,
                              const unsigned char* __restrict__ member_mask,
                              const float* __restrict__ user_table,
                              const float* __restrict__ item_table,
                              const float* __restrict__ tbl,
                              const float* __restrict__ W_bil,
                              const float* __restrict__ b_bil,
                              const float* __restrict__ W1,
                              const float* __restrict__ b1,
                              const float* __restrict__ W2,
                              const float* __restrict__ b2,
                              float* __restrict__ out, int Btot) {
    int b = blockIdx.x * blockDim.x + threadIdx.x;
    if (b >= Btot) return;

    int item = item_inputs[b];

    // Prefix mask -> length via popcount of 0x01 bytes (16B aligned).
    uint4 mv = *(const uint4*)(member_mask + (size_t)b * MM);
    int len = __popc(mv.x & 0x01010101u) + __popc(mv.y & 0x01010101u) +
              __popc(mv.z & 0x01010101u) + __popc(mv.w & 0x01010101u);

    int ids[MM];
    {
        const int4* mp = (const int4*)(member_ids + (size_t)b * MM);
#pragma unroll
        for (int q = 0; q < 4; ++q) {
            int4 v = mp[q];
            ids[4*q+0] = v.x; ids[4*q+1] = v.y; ids[4*q+2] = v.z; ids[4*q+3] = v.w;
        }
    }

    float t[DD];
    float cj[8];
    if (USE_TBL) {
        const float* tb = tbl + (size_t)item * 40;
        load8f4(tb, t);
        float4 c0 = *(const float4*)(tb + 32);
        float4 c1 = *(const float4*)(tb + 36);
        cj[0] = c0.x; cj[1] = c0.y; cj[2] = c0.z; cj[3] = c0.w;
        cj[4] = c1.x; cj[5] = c1.y; cj[6] = c1.z; cj[7] = c1.w;
    } else {
        float it0[DD];
        load8f4(item_table + (size_t)item * DD, it0);
#pragma unroll 4
        for (int d = 0; d < DD; ++d) {
            float s = 0.f;
#pragma unroll
            for (int e = 0; e < DD; ++e) s = fmaf(W_bil[d * DD + e], it0[e], s);
            t[d] = s;
        }
#pragma unroll
        for (int j = 0; j < 8; ++j) {
            float s = 0.f;
#pragma unroll
            for (int d = 0; d < DD; ++d) s = fmaf(W1[j * 96 + 64 + d], it0[d], s);
            cj[j] = s;
        }
    }

    float bb = b_bil[0];
    float fin[DD];
#pragma unroll
    for (int d = 0; d < DD; ++d) fin[d] = 0.f;

    // Single pass: score_m = mem.t + b_bil; fin += score_m * mem  (mask = skip)
    for (int m = 0; m < len; ++m) {
        float me[DD];
        load8f4(user_table + (size_t)ids[m] * DD, me);
        float s = bb;
#pragma unroll
        for (int d = 0; d < DD; ++d) s = fmaf(me[d], t[d], s);
#pragma unroll
        for (int d = 0; d < DD; ++d) fin[d] = fmaf(s, me[d], fin[d]);
    }

    float it[DD];
    load8f4(item_table + (size_t)item * DD, it);

    // MLP: h_j = relu(c_j + b1_j + sum_d W1[j,d]*(f*i)[d] + W1[j,32+d]*f[d])
    float h[8];
#pragma unroll
    for (int j = 0; j < 8; ++j) h[j] = cj[j] + b1[j];
#pragma unroll
    for (int d = 0; d < DD; ++d) {
        float f = fin[d];
        float p = f * it[d];
#pragma unroll
        for (int j = 0; j < 8; ++j) {
            h[j] = fmaf(W1[j * 96 + d], p, h[j]);
            h[j] = fmaf(W1[j * 96 + 32 + d], f, h[j]);
        }
    }
    float z = b2[0];
#pragma unroll
    for (int j = 0; j < 8; ++j) {
        float hv = h[j] > 0.f ? h[j] : 0.f;
        z = fmaf(W2[j], hv, z);
    }
    out[b] = 1.f / (1.f + __expf(-z));
}

extern "C" void kernel_launch(void* const* d_in, const int* in_sizes, int n_in,
                              void* d_out, int out_size, void* d_ws, size_t ws_size,
                              hipStream_t stream) {
    const int*           item_inputs = (const int*)d_in[0];
    const int*           member_ids  = (const int*)d_in[1];
    const unsigned char* member_mask = (const unsigned char*)d_in[2];
    const float*         user_table  = (const float*)d_in[3];
    const float*         item_table  = (const float*)d_in[4];
    const float*         W_bil       = (const float*)d_in[5];
    const float*         b_bil       = (const float*)d_in[6];
    const float*         W1          = (const float*)d_in[7];
    const float*         b1          = (const float*)d_in[8];
    const float*         W2          = (const float*)d_in[9];
    const float*         b2          = (const float*)d_in[10];
    float* out = (float*)d_out;

    int Btot = in_sizes[0];
    int NI   = in_sizes[4] / DD;

    bool use_tbl = ws_size >= (size_t)NI * 40 * sizeof(float);
    int blk = 256;
    if (use_tbl) {
        float* tbl = (float*)d_ws;
        precompute_item<<<(NI + blk - 1) / blk, blk, 0, stream>>>(item_table, W_bil, W1, tbl, NI);
        bilinear_main<true><<<(Btot + blk - 1) / blk, blk, 0, stream>>>(
            item_inputs, member_ids, member_mask, user_table, item_table, tbl,
            W_bil, b_bil, W1, b1, W2, b2, out, Btot);
    } else {
        bilinear_main<false><<<(Btot + blk - 1) / blk, blk, 0, stream>>>(
            item_inputs, member_ids, member_mask, user_table, item_table, nullptr,
            W_bil, b_bil, W1, b1, W2, b2, out, Btot);
    }
}